// Round 2
// baseline (7011.537 us; speedup 1.0000x reference)
//
#include <hip/hip_runtime.h>
#include <cstdint>
#include <cstddef>

// LSTMClassifier R2: register-resident weights + multi-WG-per-stream recurrence.
// 36 streams x 4 WGs (quarter of h-cols each), 256 thr/WG, weights preloaded into
// VGPRs as MFMA B-fragments (bf16, permuted by k_convert). Per-step h exchange via
// global memory + device-scope flag counters (threadfence/release-add, acquire-spin).
// Grid = 256 WGs = 256 CUs -> all co-resident, 1 WG/CU (deadlock-free).

constexpr int kN = 36, kH = 256, kG = 1024, kB = 32, kT = 128, kSpec = 6, kOut = 30;

typedef __bf16 bf16;
typedef __bf16 bf16x8 __attribute__((ext_vector_type(8)));
typedef float f32x4 __attribute__((ext_vector_type(4)));

__device__ __forceinline__ float sigm(float v) { return 1.f / (1.f + __expf(-v)); }
__device__ __forceinline__ float tanh_f(float v) {
  v = fminf(15.f, fmaxf(-15.f, v));
  float e = __expf(2.f * v);
  return (e - 1.f) / (e + 1.f);
}

// ---- convert + permute weights fp32 -> bf16 MFMA B-fragment order ----
// packed[n][nt][ks][lane][r] with nt in [0,64): gate col g = nt*16 + (lane&15),
// k = ks*32 + (lane>>4)*8 + r. One thread = one bf16x8 group (for each tensor).
__global__ __launch_bounds__(256) void k_convert(
    const float* __restrict__ wa, const float* __restrict__ wb, const float* __restrict__ wc,
    bf16* __restrict__ oa, bf16* __restrict__ ob, bf16* __restrict__ oc)
{
  const size_t total = (size_t)kN * 64 * 8 * 64; // 1,179,648 groups per tensor
  size_t gid = (size_t)blockIdx.x * 256 + threadIdx.x;
  if (gid >= total) return;
  const int lane = (int)(gid & 63);
  const int ks = (int)((gid >> 6) & 7);
  const int nt = (int)((gid >> 9) & 63);
  const int n = (int)(gid >> 15);
  const int g = nt * 16 + (lane & 15);
  const int k = ks * 32 + (lane >> 4) * 8;
  const size_t so = ((size_t)n * kG + g) * kH + k; // 8 consecutive fp32

  const float4 a0 = *(const float4*)(wa + so), a1 = *(const float4*)(wa + so + 4);
  const float4 b0 = *(const float4*)(wb + so), b1 = *(const float4*)(wb + so + 4);
  const float4 c0 = *(const float4*)(wc + so), c1 = *(const float4*)(wc + so + 4);
  bf16x8 va, vb, vc;
  va[0]=(bf16)a0.x; va[1]=(bf16)a0.y; va[2]=(bf16)a0.z; va[3]=(bf16)a0.w;
  va[4]=(bf16)a1.x; va[5]=(bf16)a1.y; va[6]=(bf16)a1.z; va[7]=(bf16)a1.w;
  vb[0]=(bf16)b0.x; vb[1]=(bf16)b0.y; vb[2]=(bf16)b0.z; vb[3]=(bf16)b0.w;
  vb[4]=(bf16)b1.x; vb[5]=(bf16)b1.y; vb[6]=(bf16)b1.z; vb[7]=(bf16)b1.w;
  vc[0]=(bf16)c0.x; vc[1]=(bf16)c0.y; vc[2]=(bf16)c0.z; vc[3]=(bf16)c0.w;
  vc[4]=(bf16)c1.x; vc[5]=(bf16)c1.y; vc[6]=(bf16)c1.z; vc[7]=(bf16)c1.w;
  ((bf16x8*)oa)[gid] = va;
  ((bf16x8*)ob)[gid] = vb;
  ((bf16x8*)oc)[gid] = vc;
}

// ---- layer 1: blk = q*64 + n; WG owns h-cols [q*64, q*64+64); wave owns 16 cols ----
__global__ __launch_bounds__(256, 1) void k_layer1(
    const float* __restrict__ x, const float* __restrict__ Wih1,
    const float* __restrict__ bih1, const float* __restrict__ bhh1,
    const bf16* __restrict__ pk, bf16* __restrict__ h1_all,
    unsigned int* __restrict__ f1)
{
  const int blk = blockIdx.x;
  const int n = blk & 63, q = blk >> 6;
  if (n >= kN) return;
  const int tid = threadIdx.x, wv = tid >> 6, lane = tid & 63;
  const int l15 = lane & 15, l4 = lane >> 4;
  const int col = q * 64 + wv * 16 + l15; // this lane's h-col

  __shared__ float xsh[kT][kB];
  for (int i = tid; i < kB * kT; i += 256) {
    int b = i >> 7, t = i & (kT - 1);
    xsh[t][b] = x[((size_t)b * kT + t) * kN + n];
  }

  // register-resident Whh1 B-fragments: nt(gt) = gt*16 + q*4 + wv
  bf16x8 Wh[4][8];
  {
    const bf16x8* base = (const bf16x8*)pk + (size_t)n * 32768;
#pragma unroll
    for (int gt = 0; gt < 4; ++gt)
#pragma unroll
      for (int ks = 0; ks < 8; ++ks)
        Wh[gt][ks] = base[(size_t)(gt * 16 + q * 4 + wv) * 512 + ks * 64 + lane];
  }
  float wih[4], bg[4];
#pragma unroll
  for (int gt = 0; gt < 4; ++gt) {
    int g = gt * 256 + col;
    wih[gt] = Wih1[n * kG + g];
    bg[gt] = bih1[n * kG + g] + bhh1[n * kG + g];
  }
  float cst[2][4];
#pragma unroll
  for (int mt = 0; mt < 2; ++mt)
#pragma unroll
    for (int r = 0; r < 4; ++r) cst[mt][r] = 0.f;

  unsigned int* flg = f1 + (size_t)n * kT;
  __syncthreads();

#pragma unroll 1
  for (int t = 0; t < kT; ++t) {
    f32x4 acc[2][4];
#pragma unroll
    for (int mt = 0; mt < 2; ++mt)
#pragma unroll
      for (int gt = 0; gt < 4; ++gt)
#pragma unroll
        for (int r = 0; r < 4; ++r)
          acc[mt][gt][r] = xsh[t][mt * 16 + l4 * 4 + r] * wih[gt] + bg[gt];

    if (t > 0) {
      if (tid == 0) {
        while (__hip_atomic_load(&flg[t - 1], __ATOMIC_ACQUIRE, __HIP_MEMORY_SCOPE_AGENT) < 4u)
          __builtin_amdgcn_s_sleep(1);
      }
      __syncthreads();
      __builtin_amdgcn_fence(__ATOMIC_ACQUIRE, "agent");
      const bf16* __restrict__ hp = h1_all + ((size_t)n * kT + (t - 1)) * kB * kH;
      bf16x8 A[2][8];
#pragma unroll
      for (int mt = 0; mt < 2; ++mt)
#pragma unroll
        for (int ks = 0; ks < 8; ++ks)
          A[mt][ks] = *(const bf16x8*)(hp + (size_t)(mt * 16 + l15) * kH + ks * 32 + l4 * 8);
#pragma unroll
      for (int ks = 0; ks < 8; ++ks)
#pragma unroll
        for (int gt = 0; gt < 4; ++gt) {
          acc[0][gt] = __builtin_amdgcn_mfma_f32_16x16x32_bf16(A[0][ks], Wh[gt][ks], acc[0][gt], 0, 0, 0);
          acc[1][gt] = __builtin_amdgcn_mfma_f32_16x16x32_bf16(A[1][ks], Wh[gt][ks], acc[1][gt], 0, 0, 0);
        }
    }

    bf16* __restrict__ ho = h1_all + ((size_t)n * kT + t) * kB * kH;
#pragma unroll
    for (int mt = 0; mt < 2; ++mt)
#pragma unroll
      for (int r = 0; r < 4; ++r) {
        float cc = sigm(acc[mt][1][r]) * cst[mt][r]
                 + sigm(acc[mt][0][r]) * tanh_f(acc[mt][2][r]);
        cst[mt][r] = cc;
        float hv = sigm(acc[mt][3][r]) * tanh_f(cc);
        ho[(size_t)(mt * 16 + l4 * 4 + r) * kH + col] = (bf16)hv;
      }
    __threadfence();
    __syncthreads();
    if (tid == 0)
      __hip_atomic_fetch_add(&flg[t], 1u, __ATOMIC_RELEASE, __HIP_MEMORY_SCOPE_AGENT);
  }
}

// ---- layer 2: same partition; two register weight sets; h2 rolling 2-slot buffer ----
__global__ __launch_bounds__(256, 1) void k_layer2(
    const float* __restrict__ bih2, const float* __restrict__ bhh2,
    const bf16* __restrict__ pki, const bf16* __restrict__ pkh,
    const bf16* __restrict__ h1_all, bf16* __restrict__ h2b,
    float* __restrict__ h2_final, unsigned int* __restrict__ f2)
{
  const int blk = blockIdx.x;
  const int n = blk & 63, q = blk >> 6;
  if (n >= kN) return;
  const int tid = threadIdx.x, wv = tid >> 6, lane = tid & 63;
  const int l15 = lane & 15, l4 = lane >> 4;
  const int col = q * 64 + wv * 16 + l15;

  bf16x8 Wi[4][8], Wh[4][8];
  {
    const bf16x8* bi = (const bf16x8*)pki + (size_t)n * 32768;
    const bf16x8* bh = (const bf16x8*)pkh + (size_t)n * 32768;
#pragma unroll
    for (int gt = 0; gt < 4; ++gt)
#pragma unroll
      for (int ks = 0; ks < 8; ++ks) {
        size_t o = (size_t)(gt * 16 + q * 4 + wv) * 512 + ks * 64 + lane;
        Wi[gt][ks] = bi[o];
        Wh[gt][ks] = bh[o];
      }
  }
  float bg[4];
#pragma unroll
  for (int gt = 0; gt < 4; ++gt) {
    int g = gt * 256 + col;
    bg[gt] = bih2[n * kG + g] + bhh2[n * kG + g];
  }
  float cst[2][4];
#pragma unroll
  for (int mt = 0; mt < 2; ++mt)
#pragma unroll
    for (int r = 0; r < 4; ++r) cst[mt][r] = 0.f;

  unsigned int* flg = f2 + (size_t)n * kT;

#pragma unroll 1
  for (int t = 0; t < kT; ++t) {
    // pass 1: A = h1(t) (produced by previous kernel; no flags needed)
    const bf16* __restrict__ hp1 = h1_all + ((size_t)n * kT + t) * kB * kH;
    bf16x8 A[2][8];
#pragma unroll
    for (int mt = 0; mt < 2; ++mt)
#pragma unroll
      for (int ks = 0; ks < 8; ++ks)
        A[mt][ks] = *(const bf16x8*)(hp1 + (size_t)(mt * 16 + l15) * kH + ks * 32 + l4 * 8);

    f32x4 acc[2][4];
#pragma unroll
    for (int mt = 0; mt < 2; ++mt)
#pragma unroll
      for (int gt = 0; gt < 4; ++gt)
#pragma unroll
        for (int r = 0; r < 4; ++r) acc[mt][gt][r] = bg[gt];

#pragma unroll
    for (int ks = 0; ks < 8; ++ks)
#pragma unroll
      for (int gt = 0; gt < 4; ++gt) {
        acc[0][gt] = __builtin_amdgcn_mfma_f32_16x16x32_bf16(A[0][ks], Wi[gt][ks], acc[0][gt], 0, 0, 0);
        acc[1][gt] = __builtin_amdgcn_mfma_f32_16x16x32_bf16(A[1][ks], Wi[gt][ks], acc[1][gt], 0, 0, 0);
      }

    // pass 2: A = h2(t-1) from siblings (spin AFTER pass 1 to overlap publish latency)
    if (t > 0) {
      if (tid == 0) {
        while (__hip_atomic_load(&flg[t - 1], __ATOMIC_ACQUIRE, __HIP_MEMORY_SCOPE_AGENT) < 4u)
          __builtin_amdgcn_s_sleep(1);
      }
      __syncthreads();
      __builtin_amdgcn_fence(__ATOMIC_ACQUIRE, "agent");
      const bf16* __restrict__ hp2 = h2b + ((size_t)n * 2 + ((t - 1) & 1)) * kB * kH;
#pragma unroll
      for (int mt = 0; mt < 2; ++mt)
#pragma unroll
        for (int ks = 0; ks < 8; ++ks)
          A[mt][ks] = *(const bf16x8*)(hp2 + (size_t)(mt * 16 + l15) * kH + ks * 32 + l4 * 8);
#pragma unroll
      for (int ks = 0; ks < 8; ++ks)
#pragma unroll
        for (int gt = 0; gt < 4; ++gt) {
          acc[0][gt] = __builtin_amdgcn_mfma_f32_16x16x32_bf16(A[0][ks], Wh[gt][ks], acc[0][gt], 0, 0, 0);
          acc[1][gt] = __builtin_amdgcn_mfma_f32_16x16x32_bf16(A[1][ks], Wh[gt][ks], acc[1][gt], 0, 0, 0);
        }
    }

    bf16* __restrict__ ho = h2b + ((size_t)n * 2 + (t & 1)) * kB * kH;
#pragma unroll
    for (int mt = 0; mt < 2; ++mt)
#pragma unroll
      for (int r = 0; r < 4; ++r) {
        float cc = sigm(acc[mt][1][r]) * cst[mt][r]
                 + sigm(acc[mt][0][r]) * tanh_f(acc[mt][2][r]);
        cst[mt][r] = cc;
        float hv = sigm(acc[mt][3][r]) * tanh_f(cc);
        const int m = mt * 16 + l4 * 4 + r;
        ho[(size_t)m * kH + col] = (bf16)hv;
        if (t == kT - 1) h2_final[((size_t)n * kB + m) * kH + col] = hv;
      }
    __threadfence();
    __syncthreads();
    if (tid == 0)
      __hip_atomic_fetch_add(&flg[t], 1u, __ATOMIC_RELEASE, __HIP_MEMORY_SCOPE_AGENT);
  }
}

// ---- head ----
__global__ __launch_bounds__(256) void k_head1(
    const float* __restrict__ spec, const float* __restrict__ Wspec,
    const float* __restrict__ bspec, const float* __restrict__ Wp1,
    const float* __restrict__ h2f, float* __restrict__ partial)
{
  const int kc = blockIdx.x;
  const int b = blockIdx.y;
  const int o = threadIdx.x;
  __shared__ float fs[kH];
  if (kc < kN) {
    fs[o] = h2f[((size_t)kc * kB + b) * kH + o];
  } else {
    float v = bspec[o];
#pragma unroll
    for (int s = 0; s < kSpec; ++s) v += spec[b * kSpec + s] * Wspec[s * kH + o];
    fs[o] = v;
  }
  __syncthreads();
  const float* __restrict__ wp = Wp1 + (size_t)kc * 256 * kH + o;
  float a = 0.f;
#pragma unroll 8
  for (int i = 0; i < 256; ++i) a += fs[i] * wp[(size_t)i * kH];
  partial[((size_t)kc * kB + b) * kH + o] = a;
}

__global__ __launch_bounds__(256) void k_head2(
    const float* __restrict__ bp1, const float* __restrict__ Wp2,
    const float* __restrict__ bp2, const float* __restrict__ partial,
    float* __restrict__ out)
{
  const int b = blockIdx.x;
  const int o = threadIdx.x;
  __shared__ float hid[kH];
  float a = bp1[o];
#pragma unroll
  for (int kc = 0; kc < kN + 1; ++kc) a += partial[((size_t)kc * kB + b) * kH + o];
  hid[o] = fmaxf(a, 0.f);
  __syncthreads();
  if (o < kOut) {
    float r = bp2[o];
#pragma unroll 8
    for (int h = 0; h < kH; ++h) r += hid[h] * Wp2[h * kOut + o];
    out[b * kOut + o] = r;
  }
}

extern "C" void kernel_launch(void* const* d_in, const int* in_sizes, int n_in,
                              void* d_out, int out_size, void* d_ws, size_t ws_size,
                              hipStream_t stream) {
  const float* x = (const float*)d_in[0];
  const float* spec = (const float*)d_in[1];
  const float* Wih1 = (const float*)d_in[2];
  const float* Whh1 = (const float*)d_in[3];
  const float* bih1 = (const float*)d_in[4];
  const float* bhh1 = (const float*)d_in[5];
  const float* Wih2 = (const float*)d_in[6];
  const float* Whh2 = (const float*)d_in[7];
  const float* bih2 = (const float*)d_in[8];
  const float* bhh2 = (const float*)d_in[9];
  const float* Wspec = (const float*)d_in[10];
  const float* bspec = (const float*)d_in[11];
  const float* Wp1 = (const float*)d_in[12];
  const float* bp1 = (const float*)d_in[13];
  const float* Wp2 = (const float*)d_in[14];
  const float* bp2 = (const float*)d_in[15];
  float* out = (float*)d_out;

  // ws layout (~134.6 MB): [f1|f2 flags 64KB][pk1|pk2i|pk2h bf16][h1_all bf16]
  //                        [h2_final f32][partial f32 / h2b bf16 overlay]
  unsigned int* f1 = (unsigned int*)d_ws;
  unsigned int* f2 = f1 + (size_t)kN * kT;
  const size_t WSZ = (size_t)kN * kG * kH; // 9,437,184 elems per tensor
  bf16* pk1 = (bf16*)((char*)d_ws + 65536);
  bf16* pk2i = pk1 + WSZ;
  bf16* pk2h = pk2i + WSZ;
  bf16* h1_all = pk2h + WSZ;                                       // [N][T][B][H]
  float* h2_final = (float*)(h1_all + (size_t)kN * kT * kB * kH);  // [N][B][H]
  float* partial = h2_final + (size_t)kN * kB * kH;                // [37][B][H]
  bf16* h2b = (bf16*)partial;  // overlay: h2b dead before k_head1 runs

  hipMemsetAsync(d_ws, 0, 65536, stream); // zero flags

  const size_t groups = (size_t)kN * 64 * 8 * 64;
  k_convert<<<dim3((unsigned)((groups + 255) / 256)), dim3(256), 0, stream>>>(
      Whh1, Wih2, Whh2, pk1, pk2i, pk2h);
  k_layer1<<<dim3(256), dim3(256), 0, stream>>>(x, Wih1, bih1, bhh1, pk1, h1_all, f1);
  k_layer2<<<dim3(256), dim3(256), 0, stream>>>(bih2, bhh2, pk2i, pk2h, h1_all, h2b, h2_final, f2);
  k_head1<<<dim3(kN + 1, kB), dim3(256), 0, stream>>>(spec, Wspec, bspec, Wp1, h2_final, partial);
  k_head2<<<dim3(kB), dim3(256), 0, stream>>>(bp1, Wp2, bp2, partial, out);
}

// Round 3
// 1524.510 us; speedup vs baseline: 4.5992x; 4.5992x over previous
//
#include <hip/hip_runtime.h>
#include <cstdint>
#include <cstddef>

// LSTMClassifier R3: 4 WGs/stream column split + LL packet exchange (no fences).
// Packet = {bf16 h[m][c], bf16 h[m+16][c], u32 tag=step}: relaxed agent-scope 8B
// atomics go through the coherence point -> cross-XCD visible without buffer_wbl2/inv
// L2 walks (R2's 26us/step killer). Double-buffer by step parity; skew<=1 proven by
// tag transitivity. amdgpu_waves_per_eu(1,1) forces true register residency of the
// weight B-fragments (R2: compiler sank them at 124 VGPRs targeting 4 waves/EU).

constexpr int kN = 36, kH = 256, kG = 1024, kB = 32, kT = 128, kSpec = 6, kOut = 30;
constexpr int kHP = 264; // LDS row stride in ushorts: 528B/row -> 2-way bank aliasing (free)

typedef __bf16 bf16;
typedef __bf16 bf16x8 __attribute__((ext_vector_type(8)));
typedef float f32x4 __attribute__((ext_vector_type(4)));
typedef unsigned long long u64;

__device__ __forceinline__ float sigm(float v) { return 1.f / (1.f + __expf(-v)); }
__device__ __forceinline__ float tanh_f(float v) {
  v = fminf(15.f, fmaxf(-15.f, v));
  float e = __expf(2.f * v);
  return (e - 1.f) / (e + 1.f);
}
__device__ __forceinline__ unsigned short f2bf(float f) {
  bf16 b = (bf16)f;
  return __builtin_bit_cast(unsigned short, b);
}

// ---- convert + permute weights fp32 -> bf16 MFMA B-fragment order ----
// packed[n][nt][ks][lane][r]: gate col g = nt*16 + (lane&15), k = ks*32 + (lane>>4)*8 + r.
__global__ __launch_bounds__(256) void k_convert(
    const float* __restrict__ wa, const float* __restrict__ wb, const float* __restrict__ wc,
    bf16* __restrict__ oa, bf16* __restrict__ ob, bf16* __restrict__ oc)
{
  const size_t total = (size_t)kN * 64 * 8 * 64;
  size_t gid = (size_t)blockIdx.x * 256 + threadIdx.x;
  if (gid >= total) return;
  const int lane = (int)(gid & 63);
  const int ks = (int)((gid >> 6) & 7);
  const int nt = (int)((gid >> 9) & 63);
  const int n = (int)(gid >> 15);
  const int g = nt * 16 + (lane & 15);
  const int k = ks * 32 + (lane >> 4) * 8;
  const size_t so = ((size_t)n * kG + g) * kH + k;

  const float4 a0 = *(const float4*)(wa + so), a1 = *(const float4*)(wa + so + 4);
  const float4 b0 = *(const float4*)(wb + so), b1 = *(const float4*)(wb + so + 4);
  const float4 c0 = *(const float4*)(wc + so), c1 = *(const float4*)(wc + so + 4);
  bf16x8 va, vb, vc;
  va[0]=(bf16)a0.x; va[1]=(bf16)a0.y; va[2]=(bf16)a0.z; va[3]=(bf16)a0.w;
  va[4]=(bf16)a1.x; va[5]=(bf16)a1.y; va[6]=(bf16)a1.z; va[7]=(bf16)a1.w;
  vb[0]=(bf16)b0.x; vb[1]=(bf16)b0.y; vb[2]=(bf16)b0.z; vb[3]=(bf16)b0.w;
  vb[4]=(bf16)b1.x; vb[5]=(bf16)b1.y; vb[6]=(bf16)b1.z; vb[7]=(bf16)b1.w;
  vc[0]=(bf16)c0.x; vc[1]=(bf16)c0.y; vc[2]=(bf16)c0.z; vc[3]=(bf16)c0.w;
  vc[4]=(bf16)c1.x; vc[5]=(bf16)c1.y; vc[6]=(bf16)c1.z; vc[7]=(bf16)c1.w;
  ((bf16x8*)oa)[gid] = va;
  ((bf16x8*)ob)[gid] = vb;
  ((bf16x8*)oc)[gid] = vc;
}

// Poll one step's 4096 packets (this thread owns rows j / j+16 at col=tid for j=0..15),
// stage validated values into LDS. Self-validating: no fences, no flags.
__device__ __forceinline__ void poll_stage(u64* __restrict__ base, unsigned want,
                                           int tid, unsigned short (*hs)[kHP])
{
  u64 v[16];
  unsigned got = 0;
#pragma unroll
  for (int j = 0; j < 16; ++j)
    v[j] = __hip_atomic_load(base + (size_t)j * 256 + tid, __ATOMIC_RELAXED, __HIP_MEMORY_SCOPE_AGENT);
  while (true) {
#pragma unroll
    for (int j = 0; j < 16; ++j) {
      if (!(got & (1u << j)) && (unsigned)(v[j] >> 32) == want) {
        got |= 1u << j;
        unsigned d = (unsigned)v[j];
        hs[j][tid] = (unsigned short)(d & 0xFFFFu);
        hs[j + 16][tid] = (unsigned short)(d >> 16);
      }
    }
    if (got == 0xFFFFu) break;
    __builtin_amdgcn_s_sleep(1);
#pragma unroll
    for (int j = 0; j < 16; ++j)
      if (!(got & (1u << j)))
        v[j] = __hip_atomic_load(base + (size_t)j * 256 + tid, __ATOMIC_RELAXED, __HIP_MEMORY_SCOPE_AGENT);
  }
}

// ---- layer 1: blk = q*64+n; WG owns h-cols [q*64, q*64+64); wave owns 16 cols ----
__global__ __launch_bounds__(256) __attribute__((amdgpu_waves_per_eu(1, 1)))
void k_layer1(
    const float* __restrict__ x, const float* __restrict__ Wih1,
    const float* __restrict__ bih1, const float* __restrict__ bhh1,
    const bf16* __restrict__ pk, bf16* __restrict__ h1_all,
    u64* __restrict__ pkh1)
{
  const int blk = blockIdx.x;
  const int n = blk & 63, q = blk >> 6;
  if (n >= kN) return;
  const int tid = threadIdx.x, wv = tid >> 6, lane = tid & 63;
  const int l15 = lane & 15, l4 = lane >> 4;
  const int col = q * 64 + wv * 16 + l15;

  __shared__ unsigned short hs[kB][kHP];
  __shared__ float xsh[kT][kB];
  for (int i = tid; i < kB * kT; i += 256) {
    int b = i >> 7, t = i & (kT - 1);
    xsh[t][b] = x[((size_t)b * kT + t) * kN + n];
  }

  // register-resident Whh1 B-fragments: nt(gt) = gt*16 + q*4 + wv
  bf16x8 Wh[4][8];
  {
    const bf16x8* base = (const bf16x8*)pk + (size_t)n * 32768;
#pragma unroll
    for (int gt = 0; gt < 4; ++gt)
#pragma unroll
      for (int ks = 0; ks < 8; ++ks)
        Wh[gt][ks] = base[(size_t)(gt * 16 + q * 4 + wv) * 512 + ks * 64 + lane];
  }
  float wih[4], bg[4];
#pragma unroll
  for (int gt = 0; gt < 4; ++gt) {
    int g = gt * 256 + col;
    wih[gt] = Wih1[n * kG + g];
    bg[gt] = bih1[n * kG + g] + bhh1[n * kG + g];
  }
  float cst[2][4];
#pragma unroll
  for (int mt = 0; mt < 2; ++mt)
#pragma unroll
    for (int r = 0; r < 4; ++r) cst[mt][r] = 0.f;

  u64* pkbase = pkh1 + (size_t)n * 8192; // 2 parity slots x 4096 packets
  __syncthreads();

#pragma unroll 1
  for (int t = 0; t < kT; ++t) {
    f32x4 acc[2][4];
#pragma unroll
    for (int mt = 0; mt < 2; ++mt)
#pragma unroll
      for (int gt = 0; gt < 4; ++gt)
#pragma unroll
        for (int r = 0; r < 4; ++r)
          acc[mt][gt][r] = xsh[t][mt * 16 + l4 * 4 + r] * wih[gt] + bg[gt];

    if (t > 0) {
      poll_stage(pkbase + (size_t)((t - 1) & 1) * 4096, (unsigned)t, tid, hs);
      __syncthreads(); // all lanes staged before A reads
      bf16x8 A[2][8];
#pragma unroll
      for (int mt = 0; mt < 2; ++mt)
#pragma unroll
        for (int ks = 0; ks < 8; ++ks)
          A[mt][ks] = *(const bf16x8*)&hs[mt * 16 + l15][ks * 32 + l4 * 8];
#pragma unroll
      for (int ks = 0; ks < 8; ++ks)
#pragma unroll
        for (int gt = 0; gt < 4; ++gt) {
          acc[0][gt] = __builtin_amdgcn_mfma_f32_16x16x32_bf16(A[0][ks], Wh[gt][ks], acc[0][gt], 0, 0, 0);
          acc[1][gt] = __builtin_amdgcn_mfma_f32_16x16x32_bf16(A[1][ks], Wh[gt][ks], acc[1][gt], 0, 0, 0);
        }
    }

    // cell update + LL publish (data+tag atomic per 8B packet) + archive for layer2
    float hv[2][4];
#pragma unroll
    for (int mt = 0; mt < 2; ++mt)
#pragma unroll
      for (int r = 0; r < 4; ++r) {
        float cc = sigm(acc[mt][1][r]) * cst[mt][r]
                 + sigm(acc[mt][0][r]) * tanh_f(acc[mt][2][r]);
        cst[mt][r] = cc;
        hv[mt][r] = sigm(acc[mt][3][r]) * tanh_f(cc);
      }
    u64* pub = pkbase + (size_t)(t & 1) * 4096;
#pragma unroll
    for (int r = 0; r < 4; ++r) {
      unsigned lo = f2bf(hv[0][r]), hi = f2bf(hv[1][r]);
      u64 pkt = ((u64)(unsigned)(t + 1) << 32) | ((u64)hi << 16) | lo;
      __hip_atomic_store(pub + (size_t)(l4 * 4 + r) * 256 + col, pkt,
                         __ATOMIC_RELAXED, __HIP_MEMORY_SCOPE_AGENT);
    }
    bf16* __restrict__ ho = h1_all + ((size_t)n * kT + t) * kB * kH;
#pragma unroll
    for (int mt = 0; mt < 2; ++mt)
#pragma unroll
      for (int r = 0; r < 4; ++r)
        ho[(size_t)(mt * 16 + l4 * 4 + r) * kH + col] = (bf16)hv[mt][r];
  }
}

// ---- layer 2: pass1 A=h1(t) from archive (plain loads), pass2 A=h2(t-1) via LL ----
__global__ __launch_bounds__(256) __attribute__((amdgpu_waves_per_eu(1, 1)))
void k_layer2(
    const float* __restrict__ bih2, const float* __restrict__ bhh2,
    const bf16* __restrict__ pki, const bf16* __restrict__ pkh,
    const bf16* __restrict__ h1_all, float* __restrict__ h2_final,
    u64* __restrict__ pkh2)
{
  const int blk = blockIdx.x;
  const int n = blk & 63, q = blk >> 6;
  if (n >= kN) return;
  const int tid = threadIdx.x, wv = tid >> 6, lane = tid & 63;
  const int l15 = lane & 15, l4 = lane >> 4;
  const int col = q * 64 + wv * 16 + l15;

  __shared__ unsigned short hs[kB][kHP];

  bf16x8 Wi[4][8], Wh[4][8];
  {
    const bf16x8* bi = (const bf16x8*)pki + (size_t)n * 32768;
    const bf16x8* bh = (const bf16x8*)pkh + (size_t)n * 32768;
#pragma unroll
    for (int gt = 0; gt < 4; ++gt)
#pragma unroll
      for (int ks = 0; ks < 8; ++ks) {
        size_t o = (size_t)(gt * 16 + q * 4 + wv) * 512 + ks * 64 + lane;
        Wi[gt][ks] = bi[o];
        Wh[gt][ks] = bh[o];
      }
  }
  float bg[4];
#pragma unroll
  for (int gt = 0; gt < 4; ++gt) {
    int g = gt * 256 + col;
    bg[gt] = bih2[n * kG + g] + bhh2[n * kG + g];
  }
  float cst[2][4];
#pragma unroll
  for (int mt = 0; mt < 2; ++mt)
#pragma unroll
    for (int r = 0; r < 4; ++r) cst[mt][r] = 0.f;

  u64* pkbase = pkh2 + (size_t)n * 8192;

#pragma unroll 1
  for (int t = 0; t < kT; ++t) {
    // pass 1: A = h1(t) from previous kernel's archive (independent work first —
    // hides sibling publish latency before we poll)
    const bf16* __restrict__ hp1 = h1_all + ((size_t)n * kT + t) * kB * kH;
    bf16x8 A[2][8];
#pragma unroll
    for (int mt = 0; mt < 2; ++mt)
#pragma unroll
      for (int ks = 0; ks < 8; ++ks)
        A[mt][ks] = *(const bf16x8*)(hp1 + (size_t)(mt * 16 + l15) * kH + ks * 32 + l4 * 8);

    f32x4 acc[2][4];
#pragma unroll
    for (int mt = 0; mt < 2; ++mt)
#pragma unroll
      for (int gt = 0; gt < 4; ++gt)
#pragma unroll
        for (int r = 0; r < 4; ++r) acc[mt][gt][r] = bg[gt];

#pragma unroll
    for (int ks = 0; ks < 8; ++ks)
#pragma unroll
      for (int gt = 0; gt < 4; ++gt) {
        acc[0][gt] = __builtin_amdgcn_mfma_f32_16x16x32_bf16(A[0][ks], Wi[gt][ks], acc[0][gt], 0, 0, 0);
        acc[1][gt] = __builtin_amdgcn_mfma_f32_16x16x32_bf16(A[1][ks], Wi[gt][ks], acc[1][gt], 0, 0, 0);
      }

    if (t > 0) {
      poll_stage(pkbase + (size_t)((t - 1) & 1) * 4096, (unsigned)t, tid, hs);
      __syncthreads();
#pragma unroll
      for (int mt = 0; mt < 2; ++mt)
#pragma unroll
        for (int ks = 0; ks < 8; ++ks)
          A[mt][ks] = *(const bf16x8*)&hs[mt * 16 + l15][ks * 32 + l4 * 8];
#pragma unroll
      for (int ks = 0; ks < 8; ++ks)
#pragma unroll
        for (int gt = 0; gt < 4; ++gt) {
          acc[0][gt] = __builtin_amdgcn_mfma_f32_16x16x32_bf16(A[0][ks], Wh[gt][ks], acc[0][gt], 0, 0, 0);
          acc[1][gt] = __builtin_amdgcn_mfma_f32_16x16x32_bf16(A[1][ks], Wh[gt][ks], acc[1][gt], 0, 0, 0);
        }
    }

    float hv[2][4];
#pragma unroll
    for (int mt = 0; mt < 2; ++mt)
#pragma unroll
      for (int r = 0; r < 4; ++r) {
        float cc = sigm(acc[mt][1][r]) * cst[mt][r]
                 + sigm(acc[mt][0][r]) * tanh_f(acc[mt][2][r]);
        cst[mt][r] = cc;
        hv[mt][r] = sigm(acc[mt][3][r]) * tanh_f(cc);
      }
    u64* pub = pkbase + (size_t)(t & 1) * 4096;
#pragma unroll
    for (int r = 0; r < 4; ++r) {
      unsigned lo = f2bf(hv[0][r]), hi = f2bf(hv[1][r]);
      u64 pkt = ((u64)(unsigned)(t + 1) << 32) | ((u64)hi << 16) | lo;
      __hip_atomic_store(pub + (size_t)(l4 * 4 + r) * 256 + col, pkt,
                         __ATOMIC_RELAXED, __HIP_MEMORY_SCOPE_AGENT);
    }
    if (t == kT - 1) {
#pragma unroll
      for (int mt = 0; mt < 2; ++mt)
#pragma unroll
        for (int r = 0; r < 4; ++r)
          h2_final[((size_t)n * kB + (mt * 16 + l4 * 4 + r)) * kH + col] = hv[mt][r];
    }
  }
}

// ---- head ----
__global__ __launch_bounds__(256) void k_head1(
    const float* __restrict__ spec, const float* __restrict__ Wspec,
    const float* __restrict__ bspec, const float* __restrict__ Wp1,
    const float* __restrict__ h2f, float* __restrict__ partial)
{
  const int kc = blockIdx.x;
  const int b = blockIdx.y;
  const int o = threadIdx.x;
  __shared__ float fs[kH];
  if (kc < kN) {
    fs[o] = h2f[((size_t)kc * kB + b) * kH + o];
  } else {
    float v = bspec[o];
#pragma unroll
    for (int s = 0; s < kSpec; ++s) v += spec[b * kSpec + s] * Wspec[s * kH + o];
    fs[o] = v;
  }
  __syncthreads();
  const float* __restrict__ wp = Wp1 + (size_t)kc * 256 * kH + o;
  float a = 0.f;
#pragma unroll 8
  for (int i = 0; i < 256; ++i) a += fs[i] * wp[(size_t)i * kH];
  partial[((size_t)kc * kB + b) * kH + o] = a;
}

__global__ __launch_bounds__(256) void k_head2(
    const float* __restrict__ bp1, const float* __restrict__ Wp2,
    const float* __restrict__ bp2, const float* __restrict__ partial,
    float* __restrict__ out)
{
  const int b = blockIdx.x;
  const int o = threadIdx.x;
  __shared__ float hid[kH];
  float a = bp1[o];
#pragma unroll
  for (int kc = 0; kc < kN + 1; ++kc) a += partial[((size_t)kc * kB + b) * kH + o];
  hid[o] = fmaxf(a, 0.f);
  __syncthreads();
  if (o < kOut) {
    float r = bp2[o];
#pragma unroll 8
    for (int h = 0; h < kH; ++h) r += hid[h] * Wp2[h * kOut + o];
    out[b * kOut + o] = r;
  }
}

extern "C" void kernel_launch(void* const* d_in, const int* in_sizes, int n_in,
                              void* d_out, int out_size, void* d_ws, size_t ws_size,
                              hipStream_t stream) {
  const float* x = (const float*)d_in[0];
  const float* spec = (const float*)d_in[1];
  const float* Wih1 = (const float*)d_in[2];
  const float* Whh1 = (const float*)d_in[3];
  const float* bih1 = (const float*)d_in[4];
  const float* bhh1 = (const float*)d_in[5];
  const float* Wih2 = (const float*)d_in[6];
  const float* Whh2 = (const float*)d_in[7];
  const float* bih2 = (const float*)d_in[8];
  const float* bhh2 = (const float*)d_in[9];
  const float* Wspec = (const float*)d_in[10];
  const float* bspec = (const float*)d_in[11];
  const float* Wp1 = (const float*)d_in[12];
  const float* bp1 = (const float*)d_in[13];
  const float* Wp2 = (const float*)d_in[14];
  const float* bp2 = (const float*)d_in[15];
  float* out = (float*)d_out;

  // ws layout (136.9 MB): [pk1|pk2i|pk2h bf16 56.6M][h1_all bf16 75.5M][pkh1 2.36M][pkh2 2.36M]
  // overlays (regions dead by then): h2_final -> pkh1; partial -> h1_all.
  // No memset: LL tags 1..128 never match the 0xAA poison.
  const size_t WSZ = (size_t)kN * kG * kH;
  bf16* pk1 = (bf16*)d_ws;
  bf16* pk2i = pk1 + WSZ;
  bf16* pk2h = pk2i + WSZ;
  bf16* h1_all = pk2h + WSZ;
  u64* pkh1 = (u64*)(h1_all + (size_t)kN * kT * kB * kH);
  u64* pkh2 = pkh1 + (size_t)kN * 2 * 4096;
  float* h2_final = (float*)pkh1;  // pkh1 dead once k_layer1 completes
  float* partial = (float*)h1_all; // h1_all dead once k_layer2 completes

  const size_t groups = (size_t)kN * 64 * 8 * 64;
  k_convert<<<dim3((unsigned)((groups + 255) / 256)), dim3(256), 0, stream>>>(
      Whh1, Wih2, Whh2, pk1, pk2i, pk2h);
  k_layer1<<<dim3(256), dim3(256), 0, stream>>>(x, Wih1, bih1, bhh1, pk1, h1_all, pkh1);
  k_layer2<<<dim3(256), dim3(256), 0, stream>>>(bih2, bhh2, pk2i, pk2h, h1_all, h2_final, pkh2);
  k_head1<<<dim3(kN + 1, kB), dim3(256), 0, stream>>>(spec, Wspec, bspec, Wp1, h2_final, partial);
  k_head2<<<dim3(kB), dim3(256), 0, stream>>>(bp1, Wp2, bp2, partial, out);
}